// Round 1
// baseline (243.690 us; speedup 1.0000x reference)
//
#include <hip/hip_runtime.h>

#define HIDDEN 128

// ---------------------------------------------------------------------------
// Kernel 1: C = h @ W1  (A half gets +b1 folded in)
//   h:  (N, 128) f32
//   W1: (256, 128) f32   rows 0..127 -> A (src) half, rows 128..255 -> B (dst)
//   A,B: (N, 128) f32 scratch
// Block = 256 threads, 16 nodes per block.
// wave (tid>>6) -> 4-node group; lane: half = lane>>5 (A/B), c0 = (lane&31)*4.
// ---------------------------------------------------------------------------
__global__ __launch_bounds__(256) void gemm_node_proj(
    const float* __restrict__ h, const float* __restrict__ W1,
    const float* __restrict__ b1, float* __restrict__ A, float* __restrict__ B,
    int n_nodes) {
  __shared__ float hs[16 * 128];
  const int tid = threadIdx.x;
  const int block0 = blockIdx.x * 16;

  // Stage h tile: 2048 floats, 8 per thread (2x float4), coalesced.
  {
    const int nrem = n_nodes - block0;
    const int row = tid >> 4;  // tid*8/128
    const float4* src = reinterpret_cast<const float4*>(h + (size_t)block0 * 128);
    float4* dst = reinterpret_cast<float4*>(hs);
    if (row < nrem) {
      dst[tid * 2]     = src[tid * 2];
      dst[tid * 2 + 1] = src[tid * 2 + 1];
    } else {
      dst[tid * 2]     = make_float4(0.f, 0.f, 0.f, 0.f);
      dst[tid * 2 + 1] = make_float4(0.f, 0.f, 0.f, 0.f);
    }
  }
  __syncthreads();

  const int wave = tid >> 6;        // node group 0..3
  const int lane = tid & 63;
  const int n0 = wave * 4;          // local node base
  const int half = lane >> 5;       // 0 = A (src) half, 1 = B (dst) half
  const int c0 = (lane & 31) * 4;   // column within half
  const float* w1p = W1 + (size_t)half * 128 * 128 + c0;  // + k*128 per row

  float acc[4][4];
#pragma unroll
  for (int i = 0; i < 4; ++i)
#pragma unroll
    for (int j = 0; j < 4; ++j) acc[i][j] = 0.f;

  for (int kk = 0; kk < 128; kk += 4) {
    float4 hv[4];
#pragma unroll
    for (int i = 0; i < 4; ++i)
      hv[i] = *reinterpret_cast<const float4*>(&hs[(n0 + i) * 128 + kk]);
#pragma unroll
    for (int dk = 0; dk < 4; ++dk) {
      const float4 w = *reinterpret_cast<const float4*>(w1p + (size_t)(kk + dk) * 128);
#pragma unroll
      for (int i = 0; i < 4; ++i) {
        const float hval = (dk == 0) ? hv[i].x : (dk == 1) ? hv[i].y
                         : (dk == 2) ? hv[i].z : hv[i].w;
        acc[i][0] = fmaf(hval, w.x, acc[i][0]);
        acc[i][1] = fmaf(hval, w.y, acc[i][1]);
        acc[i][2] = fmaf(hval, w.z, acc[i][2]);
        acc[i][3] = fmaf(hval, w.w, acc[i][3]);
      }
    }
  }

  // Epilogue: fold b1 into the A half, store.
  float4 bb = make_float4(0.f, 0.f, 0.f, 0.f);
  if (half == 0) bb = *reinterpret_cast<const float4*>(b1 + c0);
  float* outbase = (half == 0) ? A : B;
#pragma unroll
  for (int i = 0; i < 4; ++i) {
    const int n = block0 + n0 + i;
    if (n < n_nodes) {
      float4 v = make_float4(acc[i][0] + bb.x, acc[i][1] + bb.y,
                             acc[i][2] + bb.z, acc[i][3] + bb.w);
      *reinterpret_cast<float4*>(outbase + (size_t)n * 128 + c0) = v;
    }
  }
}

// ---------------------------------------------------------------------------
// Kernel 2: per edge, score = relu(A[src] + B[dst]) . W2 + b2
// One wave (64 lanes) per edge; lane i handles components 2i, 2i+1 (float2).
// ---------------------------------------------------------------------------
__global__ __launch_bounds__(256) void edge_score(
    const int* __restrict__ ei, const float* __restrict__ A,
    const float* __restrict__ B, const float* __restrict__ W2,
    const float* __restrict__ b2, float* __restrict__ out, int n_edges) {
  const int e = (int)((blockIdx.x * 256 + threadIdx.x) >> 6);
  const int lane = threadIdx.x & 63;
  if (e >= n_edges) return;

  const int src = ei[e];
  const int dst = ei[n_edges + e];

  const float2 a = reinterpret_cast<const float2*>(A + (size_t)src * 128)[lane];
  const float2 b = reinterpret_cast<const float2*>(B + (size_t)dst * 128)[lane];
  const float2 w = reinterpret_cast<const float2*>(W2)[lane];

  float x0 = a.x + b.x; x0 = x0 > 0.f ? x0 : 0.f;
  float x1 = a.y + b.y; x1 = x1 > 0.f ? x1 : 0.f;
  float p = fmaf(x0, w.x, x1 * w.y);

#pragma unroll
  for (int off = 32; off >= 1; off >>= 1) p += __shfl_down(p, off, 64);

  if (lane == 0) out[e] = p + b2[0];
}

// ---------------------------------------------------------------------------
// Fallback (only if d_ws is too small for A+B): fully fused per-edge compute.
// One wave per edge; lane handles output columns {lane, lane+64}.
// ---------------------------------------------------------------------------
__global__ __launch_bounds__(256) void fused_fallback(
    const float* __restrict__ h, const int* __restrict__ ei,
    const float* __restrict__ W1, const float* __restrict__ b1,
    const float* __restrict__ W2, const float* __restrict__ b2,
    float* __restrict__ out, int n_edges) {
  const int e = (int)((blockIdx.x * 256 + threadIdx.x) >> 6);
  const int lane = threadIdx.x & 63;
  if (e >= n_edges) return;
  const int src = ei[e], dst = ei[n_edges + e];
  const float* hs = h + (size_t)src * 128;
  const float* hd = h + (size_t)dst * 128;
  float acc0 = b1[lane], acc1 = b1[lane + 64];
  for (int k = 0; k < 128; ++k) {
    const float s = hs[k], d = hd[k];
    acc0 = fmaf(s, W1[k * 128 + lane], acc0);
    acc0 = fmaf(d, W1[(k + 128) * 128 + lane], acc0);
    acc1 = fmaf(s, W1[k * 128 + lane + 64], acc1);
    acc1 = fmaf(d, W1[(k + 128) * 128 + lane + 64], acc1);
  }
  acc0 = acc0 > 0.f ? acc0 : 0.f;
  acc1 = acc1 > 0.f ? acc1 : 0.f;
  float p = fmaf(acc0, W2[lane], acc1 * W2[lane + 64]);
#pragma unroll
  for (int off = 32; off >= 1; off >>= 1) p += __shfl_down(p, off, 64);
  if (lane == 0) out[e] = p + b2[0];
}

extern "C" void kernel_launch(void* const* d_in, const int* in_sizes, int n_in,
                              void* d_out, int out_size, void* d_ws, size_t ws_size,
                              hipStream_t stream) {
  const float* h  = (const float*)d_in[0];
  const int*   ei = (const int*)d_in[1];
  const float* W1 = (const float*)d_in[2];
  const float* b1 = (const float*)d_in[3];
  const float* W2 = (const float*)d_in[4];
  const float* b2 = (const float*)d_in[5];
  float* out = (float*)d_out;

  const int n_nodes = in_sizes[0] / HIDDEN;  // 100000
  const int n_edges = in_sizes[1] / 2;       // 640000

  const size_t proj_bytes = (size_t)n_nodes * HIDDEN * sizeof(float);

  if (ws_size >= 2 * proj_bytes) {
    float* A = (float*)d_ws;
    float* B = A + (size_t)n_nodes * HIDDEN;
    const int gblocks = (n_nodes + 15) / 16;
    gemm_node_proj<<<gblocks, 256, 0, stream>>>(h, W1, b1, A, B, n_nodes);
    const int eblocks = (n_edges + 3) / 4;
    edge_score<<<eblocks, 256, 0, stream>>>(ei, A, B, W2, b2, out, n_edges);
  } else {
    const int eblocks = (n_edges + 3) / 4;
    fused_fallback<<<eblocks, 256, 0, stream>>>(h, ei, W1, b1, W2, b2, out, n_edges);
  }
}

// Round 2
// 100.655 us; speedup vs baseline: 2.4210x; 2.4210x over previous
//
#include <hip/hip_runtime.h>

#define HIDDEN 128

typedef _Float16 f16x8 __attribute__((ext_vector_type(8)));
typedef _Float16 f16x2 __attribute__((ext_vector_type(2)));
typedef float f32x4 __attribute__((ext_vector_type(4)));

// ---------------------------------------------------------------------------
// Kernel 0: pack W1 (fp32, (256,128)) into fp16 MFMA B-fragments.
// Bmat (K=128, N=256): Bmat[k][n] = n<128 ? W1[k][n] : W1[128+k][n-128]
// Fragment order: Wpk[((jt*4+kt)*64 + lane)*8 + j] = Bmat[kt*32+(lane>>4)*8+j][jt*16+(lane&15)]
// Grid: 64 blocks (jt*4+kt) x 64 threads (lane).
// ---------------------------------------------------------------------------
__global__ __launch_bounds__(64) void prep_w(const float* __restrict__ W1,
                                             _Float16* __restrict__ Wpk) {
  const int blk = blockIdx.x;        // 0..63 = jt*4 + kt
  const int jt = blk >> 2;
  const int kt = blk & 3;
  const int lane = threadIdx.x;      // 0..63
  const int col = jt * 16 + (lane & 15);         // 0..255
  const int kbase = kt * 32 + (lane >> 4) * 8;   // 0..120
  f16x8 v;
#pragma unroll
  for (int j = 0; j < 8; ++j) {
    const int k = kbase + j;
    const float w = (col < HIDDEN) ? W1[k * HIDDEN + col]
                                   : W1[(HIDDEN + k) * HIDDEN + (col - HIDDEN)];
    v[j] = (_Float16)w;
  }
  *reinterpret_cast<f16x8*>(Wpk + ((size_t)blk * 64 + lane) * 8) = v;
}

// ---------------------------------------------------------------------------
// Kernel 1: MFMA GEMM  C(100k x 256) = h(100k x 128) @ Bmat(128 x 256)
// cols 0..127 -> A (fp16, + b1 folded), cols 128..255 -> B (fp16).
// Block = 256 threads = 4 waves; wave handles 16 rows; 16 col-tiles x 4 K-steps.
// mfma_f32_16x16x32_f16:
//   A: lane holds A[lane&15][(lane>>4)*8 + j]
//   B: lane holds B[(lane>>4)*8 + j][lane&15]
//   C/D: lane holds C[(lane>>4)*4 + r][lane&15]
// ---------------------------------------------------------------------------
__global__ __launch_bounds__(256) void gemm_mfma(
    const float* __restrict__ h, const _Float16* __restrict__ Wpk,
    const float* __restrict__ b1, _Float16* __restrict__ Af,
    _Float16* __restrict__ Bf, int n_nodes) {
  const int lane = threadIdx.x & 63;
  const int wave = threadIdx.x >> 6;
  const int m0 = blockIdx.x * 64 + wave * 16;
  const int row = m0 + (lane & 15);
  const int kgrp = lane >> 4;

  // A fragments: 4 K-steps of 8 fp16 each.
  f16x8 afrag[4];
  if (row < n_nodes) {
    const float* hp = h + (size_t)row * HIDDEN + kgrp * 8;
#pragma unroll
    for (int kt = 0; kt < 4; ++kt) {
      const float4 v0 = *reinterpret_cast<const float4*>(hp + kt * 32);
      const float4 v1 = *reinterpret_cast<const float4*>(hp + kt * 32 + 4);
      afrag[kt][0] = (_Float16)v0.x; afrag[kt][1] = (_Float16)v0.y;
      afrag[kt][2] = (_Float16)v0.z; afrag[kt][3] = (_Float16)v0.w;
      afrag[kt][4] = (_Float16)v1.x; afrag[kt][5] = (_Float16)v1.y;
      afrag[kt][6] = (_Float16)v1.z; afrag[kt][7] = (_Float16)v1.w;
    }
  } else {
#pragma unroll
    for (int kt = 0; kt < 4; ++kt)
#pragma unroll
      for (int j = 0; j < 8; ++j) afrag[kt][j] = (_Float16)0.f;
  }

  const int col_lo = lane & 15;
  f32x4 acc[16];
#pragma unroll
  for (int jt = 0; jt < 16; ++jt) {
    const float bias = (jt < 8) ? b1[jt * 16 + col_lo] : 0.f;
    acc[jt][0] = bias; acc[jt][1] = bias; acc[jt][2] = bias; acc[jt][3] = bias;
  }

  const f16x8* wp = reinterpret_cast<const f16x8*>(Wpk);
#pragma unroll
  for (int jt = 0; jt < 16; ++jt) {
#pragma unroll
    for (int kt = 0; kt < 4; ++kt) {
      const f16x8 bfrag = wp[(jt * 4 + kt) * 64 + lane];
      acc[jt] = __builtin_amdgcn_mfma_f32_16x16x32_f16(afrag[kt], bfrag, acc[jt], 0, 0, 0);
    }
  }

  // Epilogue: fp16 store. C row = m0 + kgrp*4 + r, col = jt*16 + col_lo.
  const int rbase = m0 + kgrp * 4;
#pragma unroll
  for (int jt = 0; jt < 16; ++jt) {
    _Float16* const outp = (jt < 8) ? Af : Bf;
    const int col = ((jt & 7) * 16) + col_lo;
#pragma unroll
    for (int r = 0; r < 4; ++r) {
      const int rw = rbase + r;
      if (rw < n_nodes) outp[(size_t)rw * HIDDEN + col] = (_Float16)acc[jt][r];
    }
  }
}

// ---------------------------------------------------------------------------
// Kernel 2: per edge, score = relu(A[src] + B[dst]) . W2 + b2
// One wave per 8 edges: 16 independent row-gathers in flight (latency hiding).
// Per edge, lane i loads f16x2 (4B) -> coalesced 256B row read.
// Merged shuffle-reduction: lanes 0..7 end with the 8 edge scores.
// ---------------------------------------------------------------------------
__global__ __launch_bounds__(256) void edge_score_v2(
    const int* __restrict__ ei, const _Float16* __restrict__ Af,
    const _Float16* __restrict__ Bf, const float* __restrict__ W2,
    const float* __restrict__ b2, float* __restrict__ out, int n_edges) {
  const int wid = (int)((blockIdx.x * 256 + threadIdx.x) >> 6);
  const int lane = threadIdx.x & 63;
  const int e0 = wid * 8;
  if (e0 >= n_edges) return;

  int srcs[8], dsts[8];
#pragma unroll
  for (int k = 0; k < 8; ++k) {
    srcs[k] = ei[e0 + k];
    dsts[k] = ei[n_edges + e0 + k];
  }

  f16x2 av[8], bv[8];
#pragma unroll
  for (int k = 0; k < 8; ++k) {
    av[k] = reinterpret_cast<const f16x2*>(Af + (size_t)srcs[k] * HIDDEN)[lane];
    bv[k] = reinterpret_cast<const f16x2*>(Bf + (size_t)dsts[k] * HIDDEN)[lane];
  }

  const float2 w2v = reinterpret_cast<const float2*>(W2)[lane];
  float p[8];
#pragma unroll
  for (int k = 0; k < 8; ++k) {
    float x0 = (float)av[k][0] + (float)bv[k][0];
    float x1 = (float)av[k][1] + (float)bv[k][1];
    x0 = fmaxf(x0, 0.f);
    x1 = fmaxf(x1, 0.f);
    p[k] = fmaf(x0, w2v.x, x1 * w2v.y);
  }

  // Merged reduction: after this, lane l (l<8) holds the full sum of p[l].
  auto mrg = [&](float a, float b, int off) {
    const float as = a + __shfl_xor(a, off, 64);
    const float bs = b + __shfl_xor(b, off, 64);
    return (lane & off) ? bs : as;
  };
  float q0 = mrg(p[0], p[1], 1);
  float q1 = mrg(p[2], p[3], 1);
  float q2 = mrg(p[4], p[5], 1);
  float q3 = mrg(p[6], p[7], 1);
  float r0 = mrg(q0, q1, 2);
  float r1 = mrg(q2, q3, 2);
  float s  = mrg(r0, r1, 4);
  s += __shfl_xor(s, 8, 64);
  s += __shfl_xor(s, 16, 64);
  s += __shfl_xor(s, 32, 64);

  if (lane < 8) out[e0 + lane] = s + b2[0];
}

// ---------------------------------------------------------------------------
// Fallback (ws too small): fused fp32 per-edge compute (round-1 version).
// ---------------------------------------------------------------------------
__global__ __launch_bounds__(256) void fused_fallback(
    const float* __restrict__ h, const int* __restrict__ ei,
    const float* __restrict__ W1, const float* __restrict__ b1,
    const float* __restrict__ W2, const float* __restrict__ b2,
    float* __restrict__ out, int n_edges) {
  const int e = (int)((blockIdx.x * 256 + threadIdx.x) >> 6);
  const int lane = threadIdx.x & 63;
  if (e >= n_edges) return;
  const int src = ei[e], dst = ei[n_edges + e];
  const float* hs = h + (size_t)src * HIDDEN;
  const float* hd = h + (size_t)dst * HIDDEN;
  float acc0 = b1[lane], acc1 = b1[lane + 64];
  for (int k = 0; k < HIDDEN; ++k) {
    const float s = hs[k], d = hd[k];
    acc0 = fmaf(s, W1[k * HIDDEN + lane], acc0);
    acc0 = fmaf(d, W1[(k + HIDDEN) * HIDDEN + lane], acc0);
    acc1 = fmaf(s, W1[k * HIDDEN + lane + 64], acc1);
    acc1 = fmaf(d, W1[(k + HIDDEN) * HIDDEN + lane + 64], acc1);
  }
  acc0 = acc0 > 0.f ? acc0 : 0.f;
  acc1 = acc1 > 0.f ? acc1 : 0.f;
  float p = fmaf(acc0, W2[lane], acc1 * W2[lane + 64]);
#pragma unroll
  for (int off = 32; off >= 1; off >>= 1) p += __shfl_down(p, off, 64);
  if (lane == 0) out[e] = p + b2[0];
}

extern "C" void kernel_launch(void* const* d_in, const int* in_sizes, int n_in,
                              void* d_out, int out_size, void* d_ws, size_t ws_size,
                              hipStream_t stream) {
  const float* h  = (const float*)d_in[0];
  const int*   ei = (const int*)d_in[1];
  const float* W1 = (const float*)d_in[2];
  const float* b1 = (const float*)d_in[3];
  const float* W2 = (const float*)d_in[4];
  const float* b2 = (const float*)d_in[5];
  float* out = (float*)d_out;

  const int n_nodes = in_sizes[0] / HIDDEN;  // 100000
  const int n_edges = in_sizes[1] / 2;       // 640000

  const size_t wpk_halfs  = 64 * 64 * 8;                       // 32768
  const size_t proj_halfs = (size_t)n_nodes * HIDDEN;          // 12.8M
  const size_t need = (wpk_halfs + 2 * proj_halfs) * sizeof(_Float16);

  if (ws_size >= need) {
    _Float16* Wpk = (_Float16*)d_ws;
    _Float16* A   = Wpk + wpk_halfs;
    _Float16* B   = A + proj_halfs;

    prep_w<<<64, 64, 0, stream>>>(W1, Wpk);

    const int gblocks = (n_nodes + 63) / 64;
    gemm_mfma<<<gblocks, 256, 0, stream>>>(h, Wpk, b1, A, B, n_nodes);

    const int nwaves = (n_edges + 7) / 8;
    const int eblocks = (nwaves + 3) / 4;
    edge_score_v2<<<eblocks, 256, 0, stream>>>(ei, A, B, W2, b2, out, n_edges);
  } else {
    const int eblocks = (n_edges + 3) / 4;
    fused_fallback<<<eblocks, 256, 0, stream>>>(h, ei, W1, b1, W2, b2, out, n_edges);
  }
}

// Round 3
// 96.631 us; speedup vs baseline: 2.5219x; 1.0416x over previous
//
#include <hip/hip_runtime.h>

#define HIDDEN 128

typedef _Float16 f16x8 __attribute__((ext_vector_type(8)));
typedef _Float16 f16x4 __attribute__((ext_vector_type(4)));
typedef _Float16 f16x2 __attribute__((ext_vector_type(2)));
typedef float f32x4 __attribute__((ext_vector_type(4)));

// ---------------------------------------------------------------------------
// Kernel 0: pack W1 (fp32, (256,128)) into fp16 MFMA fragments.
// Bmat (K=128, N=256): Bmat[k][n] = n<128 ? W1[k][n] : W1[128+k][n-128]
// Wpk[((jt*4+kt)*64 + lane)*8 + j] = Bmat[kt*32+(lane>>4)*8+j][jt*16+(lane&15)]
// This order serves as the A-operand fragment for mfma_f32_16x16x32_f16 with
// A[i][k] = Bmat^T[i][k]: lane holds A[lane&15][(lane>>4)*8+j].
// ---------------------------------------------------------------------------
__global__ __launch_bounds__(64) void prep_w(const float* __restrict__ W1,
                                             _Float16* __restrict__ Wpk) {
  const int blk = blockIdx.x;        // 0..63 = jt*4 + kt
  const int jt = blk >> 2;
  const int kt = blk & 3;
  const int lane = threadIdx.x;      // 0..63
  const int col = jt * 16 + (lane & 15);         // feature 0..255
  const int kbase = kt * 32 + (lane >> 4) * 8;   // 0..120
  f16x8 v;
#pragma unroll
  for (int j = 0; j < 8; ++j) {
    const int k = kbase + j;
    const float w = (col < HIDDEN) ? W1[k * HIDDEN + col]
                                   : W1[(HIDDEN + k) * HIDDEN + (col - HIDDEN)];
    v[j] = (_Float16)w;
  }
  *reinterpret_cast<f16x8*>(Wpk + ((size_t)blk * 64 + lane) * 8) = v;
}

// ---------------------------------------------------------------------------
// Kernel 1: MFMA GEMM with swapped operands: D[feat][node] = Wt @ h^T.
// Block = 4 waves, 64 nodes (4 node-tiles of 16). Wave w owns features
// jt = 4w..4w+3 (64 features), W-fragments persistent in VGPRs.
//   A (W): lane holds Wt[jt*16+(lane&15)][kt*32+(lane>>4)*8+j]
//   B (h): lane holds h[node_tile + (lane&15)][kt*32+(lane>>4)*8+j]
//   D:     lane holds C[node=(lane&15)][feat=jt*16+(lane>>4)*4+r]
// Epilogue: f16x4 (8B) vector stores, b1 folded into acc init.
// ---------------------------------------------------------------------------
__global__ __launch_bounds__(256) void gemm_mfma_v3(
    const float* __restrict__ h, const _Float16* __restrict__ Wpk,
    const float* __restrict__ b1, _Float16* __restrict__ Af,
    _Float16* __restrict__ Bf, int n_nodes) {
  const int lane = threadIdx.x & 63;
  const int wave = threadIdx.x >> 6;
  const int nl = lane & 15;
  const int kgrp = lane >> 4;
  const int jt0 = wave * 4;
  const int nbase = blockIdx.x * 64;

  // Persistent W fragments: 16 x f16x8 (64 VGPRs), from L2.
  const f16x8* wp = reinterpret_cast<const f16x8*>(Wpk);
  f16x8 wfrag[4][4];
#pragma unroll
  for (int j4 = 0; j4 < 4; ++j4)
#pragma unroll
    for (int kt = 0; kt < 4; ++kt)
      wfrag[j4][kt] = wp[((jt0 + j4) * 4 + kt) * 64 + lane];

  // Bias: D row = feature jt*16 + kgrp*4 + r; only the A-half (jt<8) gets b1.
  f32x4 binit[4];
#pragma unroll
  for (int j4 = 0; j4 < 4; ++j4) {
    const int jt = jt0 + j4;
    if (jt < 8) {
      binit[j4] = *reinterpret_cast<const f32x4*>(b1 + jt * 16 + kgrp * 4);
    } else {
      binit[j4][0] = 0.f; binit[j4][1] = 0.f; binit[j4][2] = 0.f; binit[j4][3] = 0.f;
    }
  }

  // Load + convert h fragments for 4 node-tiles (32 dwordx4 loads, all indep).
  f16x8 hfrag[4][4];  // [nt][kt]
#pragma unroll
  for (int nt = 0; nt < 4; ++nt) {
    const int node = nbase + nt * 16 + nl;
    const int nodec = node < n_nodes ? node : 0;  // clamp; stores are guarded
    const float* hp = h + (size_t)nodec * HIDDEN + kgrp * 8;
#pragma unroll
    for (int kt = 0; kt < 4; ++kt) {
      const float4 v0 = *reinterpret_cast<const float4*>(hp + kt * 32);
      const float4 v1 = *reinterpret_cast<const float4*>(hp + kt * 32 + 4);
      hfrag[nt][kt][0] = (_Float16)v0.x; hfrag[nt][kt][1] = (_Float16)v0.y;
      hfrag[nt][kt][2] = (_Float16)v0.z; hfrag[nt][kt][3] = (_Float16)v0.w;
      hfrag[nt][kt][4] = (_Float16)v1.x; hfrag[nt][kt][5] = (_Float16)v1.y;
      hfrag[nt][kt][6] = (_Float16)v1.z; hfrag[nt][kt][7] = (_Float16)v1.w;
    }
  }

  f32x4 acc[4][4];  // [nt][j4]
#pragma unroll
  for (int nt = 0; nt < 4; ++nt)
#pragma unroll
    for (int j4 = 0; j4 < 4; ++j4) acc[nt][j4] = binit[j4];

#pragma unroll
  for (int nt = 0; nt < 4; ++nt)
#pragma unroll
    for (int kt = 0; kt < 4; ++kt)
#pragma unroll
      for (int j4 = 0; j4 < 4; ++j4)
        acc[nt][j4] = __builtin_amdgcn_mfma_f32_16x16x32_f16(
            wfrag[j4][kt], hfrag[nt][kt], acc[nt][j4], 0, 0, 0);

  // Epilogue: lane holds feats jt*16+kgrp*4+{0..3} of node (nbase+nt*16+nl).
#pragma unroll
  for (int nt = 0; nt < 4; ++nt) {
    const int node = nbase + nt * 16 + nl;
    if (node < n_nodes) {
#pragma unroll
      for (int j4 = 0; j4 < 4; ++j4) {
        const int jt = jt0 + j4;
        _Float16* dst = ((jt < 8) ? Af : Bf) +
                        (size_t)node * HIDDEN + (jt & 7) * 16 + kgrp * 4;
        f16x4 v;
        v[0] = (_Float16)acc[nt][j4][0];
        v[1] = (_Float16)acc[nt][j4][1];
        v[2] = (_Float16)acc[nt][j4][2];
        v[3] = (_Float16)acc[nt][j4][3];
        *reinterpret_cast<f16x4*>(dst) = v;
      }
    }
  }
}

// ---------------------------------------------------------------------------
// Kernel 2: per edge, score = relu(A[src] + B[dst]) . W2 + b2
// One wave per 16 edges: 64 independent row-gathers in flight.
// Per edge, lane i loads f16x2 (4B) -> coalesced 256B row read.
// Merged butterfly reduction: lanes 0..15 end with the 16 edge scores.
// ---------------------------------------------------------------------------
__global__ __launch_bounds__(256) void edge_score_v3(
    const int* __restrict__ ei, const _Float16* __restrict__ Af,
    const _Float16* __restrict__ Bf, const float* __restrict__ W2,
    const float* __restrict__ b2, float* __restrict__ out, int n_edges) {
  const int wid = (int)((blockIdx.x * 256 + threadIdx.x) >> 6);
  const int lane = threadIdx.x & 63;
  const int e0 = wid * 16;
  if (e0 >= n_edges) return;

  int srcs[16], dsts[16];
#pragma unroll
  for (int k = 0; k < 16; ++k) {
    srcs[k] = ei[e0 + k];
    dsts[k] = ei[n_edges + e0 + k];
  }

  f16x2 av[16], bv[16];
#pragma unroll
  for (int k = 0; k < 16; ++k)
    av[k] = reinterpret_cast<const f16x2*>(Af + (size_t)srcs[k] * HIDDEN)[lane];
#pragma unroll
  for (int k = 0; k < 16; ++k)
    bv[k] = reinterpret_cast<const f16x2*>(Bf + (size_t)dsts[k] * HIDDEN)[lane];

  const float2 w2v = reinterpret_cast<const float2*>(W2)[lane];
  float p[16];
#pragma unroll
  for (int k = 0; k < 16; ++k) {
    float x0 = (float)av[k][0] + (float)bv[k][0];
    float x1 = (float)av[k][1] + (float)bv[k][1];
    x0 = fmaxf(x0, 0.f);
    x1 = fmaxf(x1, 0.f);
    p[k] = fmaf(x0, w2v.x, x1 * w2v.y);
  }

  auto mrg = [&](float a, float b, int off) {
    const float as = a + __shfl_xor(a, off, 64);
    const float bs = b + __shfl_xor(b, off, 64);
    return (lane & off) ? bs : as;
  };
  float q[8];
#pragma unroll
  for (int i = 0; i < 8; ++i) q[i] = mrg(p[2 * i], p[2 * i + 1], 1);
  float r[4];
#pragma unroll
  for (int i = 0; i < 4; ++i) r[i] = mrg(q[2 * i], q[2 * i + 1], 2);
  float s2[2];
#pragma unroll
  for (int i = 0; i < 2; ++i) s2[i] = mrg(r[2 * i], r[2 * i + 1], 4);
  float t = mrg(s2[0], s2[1], 8);
  t += __shfl_xor(t, 16, 64);
  t += __shfl_xor(t, 32, 64);

  if (lane < 16 && e0 + lane < n_edges) out[e0 + lane] = t + b2[0];
}

// ---------------------------------------------------------------------------
// Fallback (ws too small): fused fp32 per-edge compute.
// ---------------------------------------------------------------------------
__global__ __launch_bounds__(256) void fused_fallback(
    const float* __restrict__ h, const int* __restrict__ ei,
    const float* __restrict__ W1, const float* __restrict__ b1,
    const float* __restrict__ W2, const float* __restrict__ b2,
    float* __restrict__ out, int n_edges) {
  const int e = (int)((blockIdx.x * 256 + threadIdx.x) >> 6);
  const int lane = threadIdx.x & 63;
  if (e >= n_edges) return;
  const int src = ei[e], dst = ei[n_edges + e];
  const float* hs = h + (size_t)src * HIDDEN;
  const float* hd = h + (size_t)dst * HIDDEN;
  float acc0 = b1[lane], acc1 = b1[lane + 64];
  for (int k = 0; k < HIDDEN; ++k) {
    const float s = hs[k], d = hd[k];
    acc0 = fmaf(s, W1[k * HIDDEN + lane], acc0);
    acc0 = fmaf(d, W1[(k + HIDDEN) * HIDDEN + lane], acc0);
    acc1 = fmaf(s, W1[k * HIDDEN + lane + 64], acc1);
    acc1 = fmaf(d, W1[(k + HIDDEN) * HIDDEN + lane + 64], acc1);
  }
  acc0 = acc0 > 0.f ? acc0 : 0.f;
  acc1 = acc1 > 0.f ? acc1 : 0.f;
  float p = fmaf(acc0, W2[lane], acc1 * W2[lane + 64]);
#pragma unroll
  for (int off = 32; off >= 1; off >>= 1) p += __shfl_down(p, off, 64);
  if (lane == 0) out[e] = p + b2[0];
}

extern "C" void kernel_launch(void* const* d_in, const int* in_sizes, int n_in,
                              void* d_out, int out_size, void* d_ws, size_t ws_size,
                              hipStream_t stream) {
  const float* h  = (const float*)d_in[0];
  const int*   ei = (const int*)d_in[1];
  const float* W1 = (const float*)d_in[2];
  const float* b1 = (const float*)d_in[3];
  const float* W2 = (const float*)d_in[4];
  const float* b2 = (const float*)d_in[5];
  float* out = (float*)d_out;

  const int n_nodes = in_sizes[0] / HIDDEN;  // 100000
  const int n_edges = in_sizes[1] / 2;       // 640000

  const size_t wpk_halfs  = 64 * 64 * 8;                       // 32768
  const size_t proj_halfs = (size_t)n_nodes * HIDDEN;          // 12.8M
  const size_t need = (wpk_halfs + 2 * proj_halfs) * sizeof(_Float16);

  if (ws_size >= need) {
    _Float16* Wpk = (_Float16*)d_ws;
    _Float16* A   = Wpk + wpk_halfs;
    _Float16* B   = A + proj_halfs;

    prep_w<<<64, 64, 0, stream>>>(W1, Wpk);

    const int gblocks = (n_nodes + 63) / 64;
    gemm_mfma_v3<<<gblocks, 256, 0, stream>>>(h, Wpk, b1, A, B, n_nodes);

    const int nwaves = (n_edges + 15) / 16;
    const int eblocks = (nwaves + 3) / 4;
    edge_score_v3<<<eblocks, 256, 0, stream>>>(ei, A, B, W2, b2, out, n_edges);
  } else {
    const int eblocks = (n_edges + 3) / 4;
    fused_fallback<<<eblocks, 256, 0, stream>>>(h, ei, W1, b1, W2, b2, out, n_edges);
  }
}

// Round 4
// 93.197 us; speedup vs baseline: 2.6148x; 1.0368x over previous
//
#include <hip/hip_runtime.h>

#define HIDDEN 128

typedef _Float16 f16x8 __attribute__((ext_vector_type(8)));
typedef _Float16 f16x4 __attribute__((ext_vector_type(4)));
typedef _Float16 f16x2 __attribute__((ext_vector_type(2)));
typedef float f32x4 __attribute__((ext_vector_type(4)));

// ---------------------------------------------------------------------------
// Kernel 0: pack W1 (fp32, (256,128)) into fp16 MFMA fragments.
// Bmat (K=128, N=256): Bmat[k][n] = n<128 ? W1[k][n] : W1[128+k][n-128]
// Wpk[((jt*4+kt)*64 + lane)*8 + j] = Bmat[kt*32+(lane>>4)*8+j][jt*16+(lane&15)]
// Serves as A-operand fragment (A = Bmat^T): lane holds A[lane&15][(lane>>4)*8+j].
// ---------------------------------------------------------------------------
__global__ __launch_bounds__(64) void prep_w(const float* __restrict__ W1,
                                             _Float16* __restrict__ Wpk) {
  const int blk = blockIdx.x;        // 0..63 = jt*4 + kt
  const int jt = blk >> 2;
  const int kt = blk & 3;
  const int lane = threadIdx.x;      // 0..63
  const int col = jt * 16 + (lane & 15);         // feature 0..255
  const int kbase = kt * 32 + (lane >> 4) * 8;   // 0..120
  f16x8 v;
#pragma unroll
  for (int j = 0; j < 8; ++j) {
    const int k = kbase + j;
    const float w = (col < HIDDEN) ? W1[k * HIDDEN + col]
                                   : W1[(HIDDEN + k) * HIDDEN + (col - HIDDEN)];
    v[j] = (_Float16)w;
  }
  *reinterpret_cast<f16x8*>(Wpk + ((size_t)blk * 64 + lane) * 8) = v;
}

// ---------------------------------------------------------------------------
// Kernel 1 (v4): persistent grid-stride MFMA GEMM, software-pipelined.
// D[feat][node] = Wt @ h^T per 16-node tile. Wave w owns features
// jt = 4w..4w+3; W-fragments + bias persistent in VGPRs across the loop.
// Pipeline: while tile t's MFMAs/stores issue, tile t+1's 8 dwordx4 h-loads
// are in flight; cvt after the wait, then immediately issue t+2.
// ---------------------------------------------------------------------------
__global__ __launch_bounds__(256, 3) void gemm_mfma_v4(
    const float* __restrict__ h, const _Float16* __restrict__ Wpk,
    const float* __restrict__ b1, _Float16* __restrict__ Af,
    _Float16* __restrict__ Bf, int n_nodes, int ntiles) {
  const int lane = threadIdx.x & 63;
  const int wave = threadIdx.x >> 6;
  const int nl = lane & 15;
  const int kgrp = lane >> 4;
  const int jt0 = wave * 4;

  // Persistent W fragments: 16 x f16x8 (64 VGPRs), L2-resident source.
  const f16x8* wp = reinterpret_cast<const f16x8*>(Wpk);
  f16x8 wfrag[4][4];
#pragma unroll
  for (int j4 = 0; j4 < 4; ++j4)
#pragma unroll
    for (int kt = 0; kt < 4; ++kt)
      wfrag[j4][kt] = wp[((jt0 + j4) * 4 + kt) * 64 + lane];

  // Persistent bias (A-half only).
  f32x4 binit[4];
#pragma unroll
  for (int j4 = 0; j4 < 4; ++j4) {
    const int jt = jt0 + j4;
    if (jt < 8) {
      binit[j4] = *reinterpret_cast<const f32x4*>(b1 + jt * 16 + kgrp * 4);
    } else {
      binit[j4][0] = 0.f; binit[j4][1] = 0.f; binit[j4][2] = 0.f; binit[j4][3] = 0.f;
    }
  }

  float4 buf[8];     // raw fp32 loads for the NEXT tile (in flight)
  f16x8 hfrag[4];    // converted fragments for the CURRENT tile

  auto LOAD = [&](int tile) {
    int node = tile * 16 + nl;
    if (node >= n_nodes) node = 0;  // clamp; stores are guarded
    const float4* hp = reinterpret_cast<const float4*>(h) +
                       (size_t)node * 32 + kgrp * 2;
#pragma unroll
    for (int kt = 0; kt < 4; ++kt) {
      buf[kt * 2]     = hp[kt * 8];
      buf[kt * 2 + 1] = hp[kt * 8 + 1];
    }
  };

  auto CVT = [&]() {
#pragma unroll
    for (int kt = 0; kt < 4; ++kt) {
      const float4 v0 = buf[kt * 2];
      const float4 v1 = buf[kt * 2 + 1];
      hfrag[kt][0] = (_Float16)v0.x; hfrag[kt][1] = (_Float16)v0.y;
      hfrag[kt][2] = (_Float16)v0.z; hfrag[kt][3] = (_Float16)v0.w;
      hfrag[kt][4] = (_Float16)v1.x; hfrag[kt][5] = (_Float16)v1.y;
      hfrag[kt][6] = (_Float16)v1.z; hfrag[kt][7] = (_Float16)v1.w;
    }
  };

  auto COMPUTE_STORE = [&](int tile) {
    f32x4 acc[4];
#pragma unroll
    for (int j4 = 0; j4 < 4; ++j4) acc[j4] = binit[j4];
#pragma unroll
    for (int kt = 0; kt < 4; ++kt)
#pragma unroll
      for (int j4 = 0; j4 < 4; ++j4)
        acc[j4] = __builtin_amdgcn_mfma_f32_16x16x32_f16(
            wfrag[j4][kt], hfrag[kt], acc[j4], 0, 0, 0);
    const int node = tile * 16 + nl;
    if (node < n_nodes) {
#pragma unroll
      for (int j4 = 0; j4 < 4; ++j4) {
        const int jt = jt0 + j4;
        _Float16* dst = ((jt < 8) ? Af : Bf) +
                        (size_t)node * HIDDEN + (jt & 7) * 16 + kgrp * 4;
        f16x4 v;
        v[0] = (_Float16)acc[j4][0];
        v[1] = (_Float16)acc[j4][1];
        v[2] = (_Float16)acc[j4][2];
        v[3] = (_Float16)acc[j4][3];
        *reinterpret_cast<f16x4*>(dst) = v;
      }
    }
  };

  const int stride = gridDim.x;
  int tile = blockIdx.x;
  if (tile >= ntiles) return;

  LOAD(tile);          // loads for t in flight
  CVT();               // wait + convert t
  int next = tile + stride;
  if (next < ntiles) LOAD(next);  // t+1 in flight

  while (true) {
    COMPUTE_STORE(tile);          // MFMA + stores for t (loads for t+1 flying)
    if (next >= ntiles) break;
    CVT();                        // wait + convert t+1
    const int next2 = next + stride;
    if (next2 < ntiles) LOAD(next2);  // t+2 in flight
    tile = next;
    next = next2;
  }
}

// ---------------------------------------------------------------------------
// Kernel 2: per edge, score = relu(A[src] + B[dst]) . W2 + b2
// One wave per 16 edges: 64 independent row-gathers in flight.
// Per edge, lane i loads f16x2 (4B) -> coalesced 256B row read.
// Merged butterfly reduction: lanes 0..15 end with the 16 edge scores.
// ---------------------------------------------------------------------------
__global__ __launch_bounds__(256) void edge_score_v3(
    const int* __restrict__ ei, const _Float16* __restrict__ Af,
    const _Float16* __restrict__ Bf, const float* __restrict__ W2,
    const float* __restrict__ b2, float* __restrict__ out, int n_edges) {
  const int wid = (int)((blockIdx.x * 256 + threadIdx.x) >> 6);
  const int lane = threadIdx.x & 63;
  const int e0 = wid * 16;
  if (e0 >= n_edges) return;

  int srcs[16], dsts[16];
#pragma unroll
  for (int k = 0; k < 16; ++k) {
    srcs[k] = ei[e0 + k];
    dsts[k] = ei[n_edges + e0 + k];
  }

  f16x2 av[16], bv[16];
#pragma unroll
  for (int k = 0; k < 16; ++k)
    av[k] = reinterpret_cast<const f16x2*>(Af + (size_t)srcs[k] * HIDDEN)[lane];
#pragma unroll
  for (int k = 0; k < 16; ++k)
    bv[k] = reinterpret_cast<const f16x2*>(Bf + (size_t)dsts[k] * HIDDEN)[lane];

  const float2 w2v = reinterpret_cast<const float2*>(W2)[lane];
  float p[16];
#pragma unroll
  for (int k = 0; k < 16; ++k) {
    float x0 = (float)av[k][0] + (float)bv[k][0];
    float x1 = (float)av[k][1] + (float)bv[k][1];
    x0 = fmaxf(x0, 0.f);
    x1 = fmaxf(x1, 0.f);
    p[k] = fmaf(x0, w2v.x, x1 * w2v.y);
  }

  auto mrg = [&](float a, float b, int off) {
    const float as = a + __shfl_xor(a, off, 64);
    const float bs = b + __shfl_xor(b, off, 64);
    return (lane & off) ? bs : as;
  };
  float q[8];
#pragma unroll
  for (int i = 0; i < 8; ++i) q[i] = mrg(p[2 * i], p[2 * i + 1], 1);
  float r[4];
#pragma unroll
  for (int i = 0; i < 4; ++i) r[i] = mrg(q[2 * i], q[2 * i + 1], 2);
  float s2[2];
#pragma unroll
  for (int i = 0; i < 2; ++i) s2[i] = mrg(r[2 * i], r[2 * i + 1], 4);
  float t = mrg(s2[0], s2[1], 8);
  t += __shfl_xor(t, 16, 64);
  t += __shfl_xor(t, 32, 64);

  if (lane < 16 && e0 + lane < n_edges) out[e0 + lane] = t + b2[0];
}

// ---------------------------------------------------------------------------
// Fallback (ws too small): fused fp32 per-edge compute.
// ---------------------------------------------------------------------------
__global__ __launch_bounds__(256) void fused_fallback(
    const float* __restrict__ h, const int* __restrict__ ei,
    const float* __restrict__ W1, const float* __restrict__ b1,
    const float* __restrict__ W2, const float* __restrict__ b2,
    float* __restrict__ out, int n_edges) {
  const int e = (int)((blockIdx.x * 256 + threadIdx.x) >> 6);
  const int lane = threadIdx.x & 63;
  if (e >= n_edges) return;
  const int src = ei[e], dst = ei[n_edges + e];
  const float* hs = h + (size_t)src * HIDDEN;
  const float* hd = h + (size_t)dst * HIDDEN;
  float acc0 = b1[lane], acc1 = b1[lane + 64];
  for (int k = 0; k < HIDDEN; ++k) {
    const float s = hs[k], d = hd[k];
    acc0 = fmaf(s, W1[k * HIDDEN + lane], acc0);
    acc0 = fmaf(d, W1[(k + HIDDEN) * HIDDEN + lane], acc0);
    acc1 = fmaf(s, W1[k * HIDDEN + lane + 64], acc1);
    acc1 = fmaf(d, W1[(k + HIDDEN) * HIDDEN + lane + 64], acc1);
  }
  acc0 = acc0 > 0.f ? acc0 : 0.f;
  acc1 = acc1 > 0.f ? acc1 : 0.f;
  float p = fmaf(acc0, W2[lane], acc1 * W2[lane + 64]);
#pragma unroll
  for (int off = 32; off >= 1; off >>= 1) p += __shfl_down(p, off, 64);
  if (lane == 0) out[e] = p + b2[0];
}

extern "C" void kernel_launch(void* const* d_in, const int* in_sizes, int n_in,
                              void* d_out, int out_size, void* d_ws, size_t ws_size,
                              hipStream_t stream) {
  const float* h  = (const float*)d_in[0];
  const int*   ei = (const int*)d_in[1];
  const float* W1 = (const float*)d_in[2];
  const float* b1 = (const float*)d_in[3];
  const float* W2 = (const float*)d_in[4];
  const float* b2 = (const float*)d_in[5];
  float* out = (float*)d_out;

  const int n_nodes = in_sizes[0] / HIDDEN;  // 100000
  const int n_edges = in_sizes[1] / 2;       // 640000

  const size_t wpk_halfs  = 64 * 64 * 8;                       // 32768
  const size_t proj_halfs = (size_t)n_nodes * HIDDEN;          // 12.8M
  const size_t need = (wpk_halfs + 2 * proj_halfs) * sizeof(_Float16);

  if (ws_size >= need) {
    _Float16* Wpk = (_Float16*)d_ws;
    _Float16* A   = Wpk + wpk_halfs;
    _Float16* B   = A + proj_halfs;

    prep_w<<<64, 64, 0, stream>>>(W1, Wpk);

    const int ntiles = (n_nodes + 15) / 16;       // 6250
    const int gblocks = ntiles < 768 ? ntiles : 768;
    gemm_mfma_v4<<<gblocks, 256, 0, stream>>>(h, Wpk, b1, A, B, n_nodes, ntiles);

    const int nwaves = (n_edges + 15) / 16;
    const int eblocks = (nwaves + 3) / 4;
    edge_score_v3<<<eblocks, 256, 0, stream>>>(ei, A, B, W2, b2, out, n_edges);
  } else {
    const int eblocks = (n_edges + 3) / 4;
    fused_fallback<<<eblocks, 256, 0, stream>>>(h, ei, W1, b1, W2, b2, out, n_edges);
  }
}